// Round 1
// baseline (1598.799 us; speedup 1.0000x reference)
//
#include <hip/hip_runtime.h>
#include <math.h>

// Conv3DCapsuleLayer: fused implicit-GEMM conv3d (fp32) + 3-iter dynamic routing.
// input_tensor (2,24,24,24,8,32) f32 | W (3,3,3,32,256) f32 | b (1,1,1,8,32) f32
// out = activation (2,24,24,24,8,32) f32
//
// Conv rows n=0..15 map to input (b_in = n&1, ic_in = n>>1)  [x = transpose(4,0,1,2,3,5)]
// Routing votes[b2][ic2] = conv row n = b2*8 + ic2           [reshape relabel]

#define SPT 13824   // 24*24*24

__device__ __forceinline__ float red32(float v) {
  v += __shfl_xor(v, 16);
  v += __shfl_xor(v, 8);
  v += __shfl_xor(v, 4);
  v += __shfl_xor(v, 2);
  v += __shfl_xor(v, 1);
  return v;
}

__global__ __launch_bounds__(256, 3)
void caps_fused(const float* __restrict__ xg, const float* __restrict__ Wg,
                const float* __restrict__ bg, float* __restrict__ outg) {
  // LDS layout (floats):
  //  GEMM phase:  smA [32][68] = 2176   | smB [32][256] = 8192   (base..10367)
  //  Route phase: smV [32][256] = 8192  (aliases base)           | smL [8][8] at 10368
  __shared__ __align__(16) float sm[10432];   // 41728 B -> 3 blocks/CU
  float* smA = sm;
  float* smB = sm + 2176;
  float* smV = sm;
  float* smL = sm + 10368;

  const int t    = threadIdx.x;
  const int blk  = blockIdx.x;          // 0..3455
  const int rbase = blk * 8;            // global output row base (b2*13824 + pos)
  const int b2   = rbase / SPT;
  const int posb = rbase % SPT;         // multiple of 8, never crosses a y-row
  const int z  = posb / 576;
  const int y  = (posb % 576) / 24;
  const int x0 = posb % 24;

  // GEMM thread tile: 4 rows x 16 cols
  const int pix_t = t >> 4;             // 0..15 -> rows pix_t*4..+3
  const int oc_t  = t & 15;             // cols oc_t*4 + {0,64,128,192} + 0..3

  // A-staging mapping: thread loads row am, cin acin..acin+7
  const int am    = t >> 2;             // 0..63
  const int acin  = (t & 3) * 8;
  const int a_pl  = am >> 3;            // pos_local of this row
  const int a_n   = b2 * 8 + (am & 7);  // conv row n
  const int a_bin = a_n & 1;
  const int a_icin = a_n >> 1;

  float acc[4][16];
  #pragma unroll
  for (int i = 0; i < 4; ++i)
    #pragma unroll
    for (int j = 0; j < 16; ++j) acc[i][j] = 0.f;

  #pragma unroll 1
  for (int tap = 0; tap < 27; ++tap) {
    const int dz = tap / 9, dy = (tap % 9) / 3, dx = tap % 3;
    const int zz = z + dz - 1;
    const int yy = y + dy - 1;
    const int xx = x0 + a_pl + dx - 1;

    float4 va = {0.f, 0.f, 0.f, 0.f}, vb = {0.f, 0.f, 0.f, 0.f};
    if ((unsigned)zz < 24u && (unsigned)yy < 24u && (unsigned)xx < 24u) {
      const float* src = xg + ((((a_bin * 24 + zz) * 24 + yy) * 24 + xx) * 8 + a_icin) * 32 + acin;
      va = *(const float4*)src;
      vb = *(const float4*)(src + 4);
    }
    float4 w[8];
    const float* wsrc = Wg + tap * 8192 + t * 4;
    #pragma unroll
    for (int k = 0; k < 8; ++k) w[k] = *(const float4*)(wsrc + k * 1024);

    __syncthreads();   // previous iteration's LDS reads complete
    smA[(acin + 0) * 68 + am] = va.x;
    smA[(acin + 1) * 68 + am] = va.y;
    smA[(acin + 2) * 68 + am] = va.z;
    smA[(acin + 3) * 68 + am] = va.w;
    smA[(acin + 4) * 68 + am] = vb.x;
    smA[(acin + 5) * 68 + am] = vb.y;
    smA[(acin + 6) * 68 + am] = vb.z;
    smA[(acin + 7) * 68 + am] = vb.w;
    #pragma unroll
    for (int k = 0; k < 8; ++k) *(float4*)&smB[k * 1024 + t * 4] = w[k];
    __syncthreads();

    #pragma unroll 8
    for (int cin = 0; cin < 32; ++cin) {
      const float4 a4  = *(const float4*)&smA[cin * 68 + pix_t * 4];
      const float4 b0  = *(const float4*)&smB[cin * 256 + oc_t * 4];
      const float4 b1  = *(const float4*)&smB[cin * 256 + oc_t * 4 + 64];
      const float4 b2v = *(const float4*)&smB[cin * 256 + oc_t * 4 + 128];
      const float4 b3v = *(const float4*)&smB[cin * 256 + oc_t * 4 + 192];
      const float ar[4] = {a4.x, a4.y, a4.z, a4.w};
      #pragma unroll
      for (int i = 0; i < 4; ++i) {
        acc[i][0]  = fmaf(ar[i], b0.x,  acc[i][0]);
        acc[i][1]  = fmaf(ar[i], b0.y,  acc[i][1]);
        acc[i][2]  = fmaf(ar[i], b0.z,  acc[i][2]);
        acc[i][3]  = fmaf(ar[i], b0.w,  acc[i][3]);
        acc[i][4]  = fmaf(ar[i], b1.x,  acc[i][4]);
        acc[i][5]  = fmaf(ar[i], b1.y,  acc[i][5]);
        acc[i][6]  = fmaf(ar[i], b1.z,  acc[i][6]);
        acc[i][7]  = fmaf(ar[i], b1.w,  acc[i][7]);
        acc[i][8]  = fmaf(ar[i], b2v.x, acc[i][8]);
        acc[i][9]  = fmaf(ar[i], b2v.y, acc[i][9]);
        acc[i][10] = fmaf(ar[i], b2v.z, acc[i][10]);
        acc[i][11] = fmaf(ar[i], b2v.w, acc[i][11]);
        acc[i][12] = fmaf(ar[i], b3v.x, acc[i][12]);
        acc[i][13] = fmaf(ar[i], b3v.y, acc[i][13]);
        acc[i][14] = fmaf(ar[i], b3v.z, acc[i][14]);
        acc[i][15] = fmaf(ar[i], b3v.w, acc[i][15]);
      }
    }
  }
  __syncthreads();   // all GEMM LDS reads done before aliasing as V

  // ---------------- routing ----------------
  const int c = t >> 5;     // capsule 0..7
  const int a = t & 31;     // atom 0..31
  const float bia = bg[t];

  #pragma unroll 1
  for (int pass = 0; pass < 2; ++pass) {
    // dump this half's votes (rows m = pass*32 .. +31) to LDS
    if ((pix_t >> 3) == pass) {
      const int rl = (pix_t & 7) * 4;
      #pragma unroll
      for (int i = 0; i < 4; ++i) {
        #pragma unroll
        for (int jj = 0; jj < 4; ++jj) {
          float4 v4 = {acc[i][jj * 4 + 0], acc[i][jj * 4 + 1],
                       acc[i][jj * 4 + 2], acc[i][jj * 4 + 3]};
          *(float4*)&smV[(rl + i) * 256 + oc_t * 4 + jj * 64] = v4;
        }
      }
    }
    __syncthreads();

    #pragma unroll 1
    for (int pp = 0; pp < 4; ++pp) {
      const int pl = pass * 4 + pp;     // pos_local 0..7
      float v[8];
      #pragma unroll
      for (int ic = 0; ic < 8; ++ic) v[ic] = smV[(pp * 8 + ic) * 256 + t];

      float route[8];
      #pragma unroll 1
      for (int it = 0; it < 3; ++it) {
        if (it == 0) {
          #pragma unroll
          for (int ic = 0; ic < 8; ++ic) route[ic] = 0.125f;
        } else {
          #pragma unroll
          for (int ic = 0; ic < 8; ++ic) {
            float mx = -3.4e38f;
            #pragma unroll
            for (int cc = 0; cc < 8; ++cc) mx = fmaxf(mx, smL[ic * 8 + cc]);
            float s = 0.f;
            #pragma unroll
            for (int cc = 0; cc < 8; ++cc) s += __expf(smL[ic * 8 + cc] - mx);
            route[ic] = __expf(smL[ic * 8 + c] - mx) / s;
          }
        }
        float pre = bia;
        #pragma unroll
        for (int ic = 0; ic < 8; ++ic) pre = fmaf(route[ic], v[ic], pre);

        float ns = red32(pre * pre);          // ||preactivate||^2 over atoms
        const float nrm = sqrtf(ns);
        const float act = pre * (nrm / (1.0f + ns));   // squash

        if (it == 2) {
          outg[(rbase + pl) * 256 + t] = act;
        } else {
          float d[8];
          #pragma unroll
          for (int ic = 0; ic < 8; ++ic) d[ic] = red32(v[ic] * act);
          __syncthreads();   // all route reads of smL done before update
          if (a == 0) {
            #pragma unroll
            for (int ic = 0; ic < 8; ++ic)
              smL[ic * 8 + c] = (it == 0) ? d[ic] : smL[ic * 8 + c] + d[ic];
          }
          __syncthreads();   // logits visible for next iteration
        }
      }
    }
    __syncthreads();   // V reads done before next pass overwrites
  }
}

extern "C" void kernel_launch(void* const* d_in, const int* in_sizes, int n_in,
                              void* d_out, int out_size, void* d_ws, size_t ws_size,
                              hipStream_t stream) {
  const float* x = (const float*)d_in[0];
  const float* W = (const float*)d_in[1];
  const float* b = (const float*)d_in[2];
  float* out = (float*)d_out;
  (void)d_ws; (void)ws_size; (void)in_sizes; (void)n_in; (void)out_size;
  caps_fused<<<dim3(3456), dim3(256), 0, stream>>>(x, W, b, out);
}

// Round 3
// 973.621 us; speedup vs baseline: 1.6421x; 1.6421x over previous
//
#include <hip/hip_runtime.h>
#include <math.h>

// Conv3DCapsuleLayer: fp16-MFMA implicit-GEMM conv3d + fused 3-iter dynamic routing.
// input_tensor (2,24,24,24,8,32) f32 | W (3,3,3,32,256) f32 | b (1,1,1,8,32) f32
// out = activation (2,24,24,24,8,32) f32
//
// Conv rows n=0..15 map to input (b_in = n&1, ic_in = n>>1)
// Routing votes[b2][ic2] = conv row n = b2*8 + ic2
//
// Block = 64 rows (8 pos x 8 ic) x 256 cols, K = 27 taps x 32.
// fp16 (not bf16): 10-bit mantissa keeps conv absmax ~3e-3 < 1.5e-2 threshold
// (bf16 measured 2.36e-2 — fails). Same shape/rate/fragment layout on gfx950.
// A: fp32->fp16 convert on stage, fragment-linear LDS (frag read = base+lane*16).
// B: W pre-converted to tap-major fragment-linear fp16 in d_ws (prep_W), staged
//    per tap with 16B global_load_lds. Double-buffered, 1 barrier/tap.

#define SPT 13824   // 24*24*24

typedef __attribute__((ext_vector_type(8))) _Float16 half8;
typedef __attribute__((ext_vector_type(4))) float f32x4;

__device__ __forceinline__ float red32(float v) {
  v += __shfl_xor(v, 16);
  v += __shfl_xor(v, 8);
  v += __shfl_xor(v, 4);
  v += __shfl_xor(v, 2);
  v += __shfl_xor(v, 1);
  return v;
}

// W (3,3,3,32,256) fp32 -> Wh[tap][cb(16)][slot(64)][8] fp16, slot = kg*16+nr:
// element (k = kg*8+j, n = cb*16+nr). This is exactly the MFMA B-fragment order.
__global__ void prep_W(const float* __restrict__ W, _Float16* __restrict__ Wh) {
  const int tap = blockIdx.x;
  #pragma unroll
  for (int rep = 0; rep < 4; ++rep) {
    const int idx = rep * 256 + threadIdx.x;   // 0..1023
    const int cb = idx >> 6;
    const int kg = (idx >> 4) & 3;
    const int nr = idx & 15;
    const int n  = cb * 16 + nr;
    half8 o;
    #pragma unroll
    for (int j = 0; j < 8; ++j)
      o[j] = (_Float16)W[(tap * 32 + kg * 8 + j) * 256 + n];
    *(half8*)(Wh + tap * 8192 + idx * 8) = o;
  }
}

__global__ __launch_bounds__(256, 3)
void caps_mfma(const float* __restrict__ xg, const _Float16* __restrict__ Wh,
               const float* __restrict__ bg, float* __restrict__ outg) {
  // LDS bytes: bufA[b] at b*20480 (4 KB), bufB[b] at b*20480+4096 (16 KB)
  // Routing aliases: smV f32 [32][264] at 0 (33792 B), smL at 40960 (256 B)
  __shared__ __align__(16) unsigned char lds[41216];
  float* smV = (float*)lds;
  float* smL = (float*)(lds + 40960);

  const int t    = threadIdx.x;
  const int lane = t & 63;
  const int w    = t >> 6;
  const int rbase = blockIdx.x * 8;
  const int b2   = rbase / SPT;
  const int posb = rbase % SPT;
  const int z  = posb / 576;
  const int y  = (posb % 576) / 24;
  const int x0 = posb % 24;

  // A staging: thread t -> row arow (0..63), k-group akg; writes 16B to frag-linear slot
  const int arow  = t >> 2;
  const int akg   = t & 3;
  const int apl   = arow >> 3;
  const int aic   = arow & 7;
  const int an    = b2 * 8 + aic;
  const int abin  = an & 1;
  const int aicin = an >> 1;
  const int aoff  = (arow >> 4) * 1024 + (akg * 16 + (arow & 15)) * 16; // bytes in bufA

  f32x4 acc[4][4];
  #pragma unroll
  for (int mi = 0; mi < 4; ++mi)
    #pragma unroll
    for (int ni = 0; ni < 4; ++ni) acc[mi][ni] = (f32x4){0.f, 0.f, 0.f, 0.f};

  // ---- prologue: stage tap 0 into buf 0 ----
  {
    const int zz = z - 1, yy = y - 1, xx = x0 + apl - 1;
    float4 va = {0,0,0,0}, vb = {0,0,0,0};
    if ((unsigned)zz < 24u && (unsigned)yy < 24u && (unsigned)xx < 24u) {
      const float* src = xg + ((((abin * 24 + zz) * 24 + yy) * 24 + xx) * 8 + aicin) * 32 + akg * 8;
      va = *(const float4*)src;
      vb = *(const float4*)(src + 4);
    }
    half8 o;
    o[0]=(_Float16)va.x; o[1]=(_Float16)va.y; o[2]=(_Float16)va.z; o[3]=(_Float16)va.w;
    o[4]=(_Float16)vb.x; o[5]=(_Float16)vb.y; o[6]=(_Float16)vb.z; o[7]=(_Float16)vb.w;
    *(half8*)(lds + aoff) = o;
    const _Float16* bsrc = Wh + w * 2048 + lane * 8;
    #pragma unroll
    for (int i = 0; i < 4; ++i)
      __builtin_amdgcn_global_load_lds(
        (const __attribute__((address_space(1))) unsigned int*)(bsrc + i * 512),
        (__attribute__((address_space(3))) unsigned int*)(lds + 4096 + w * 4096 + i * 1024),
        16, 0, 0);
  }
  __syncthreads();

  int cur = 0;
  #pragma unroll 1
  for (int tap = 0; tap < 27; ++tap) {
    const int nxt = tap + 1;
    float4 va = {0,0,0,0}, vb = {0,0,0,0};
    if (nxt < 27) {
      const int dz = nxt / 9, dy = (nxt % 9) / 3, dx = nxt % 3;
      const int zz = z + dz - 1, yy = y + dy - 1, xx = x0 + apl + dx - 1;
      if ((unsigned)zz < 24u && (unsigned)yy < 24u && (unsigned)xx < 24u) {
        const float* src = xg + ((((abin * 24 + zz) * 24 + yy) * 24 + xx) * 8 + aicin) * 32 + akg * 8;
        va = *(const float4*)src;
        vb = *(const float4*)(src + 4);
      }
      const _Float16* bsrc = Wh + nxt * 8192 + w * 2048 + lane * 8;
      unsigned char* bdst = lds + (cur ^ 1) * 20480 + 4096 + w * 4096;
      #pragma unroll
      for (int i = 0; i < 4; ++i)
        __builtin_amdgcn_global_load_lds(
          (const __attribute__((address_space(1))) unsigned int*)(bsrc + i * 512),
          (__attribute__((address_space(3))) unsigned int*)(bdst + i * 1024),
          16, 0, 0);
    }

    const unsigned char* pA = lds + cur * 20480;
    const unsigned char* pB = lds + cur * 20480 + 4096 + w * 4096;
    half8 af[4], bfr[4];
    #pragma unroll
    for (int mi = 0; mi < 4; ++mi) af[mi]  = *(const half8*)(pA + mi * 1024 + lane * 16);
    #pragma unroll
    for (int ni = 0; ni < 4; ++ni) bfr[ni] = *(const half8*)(pB + ni * 1024 + lane * 16);
    #pragma unroll
    for (int mi = 0; mi < 4; ++mi)
      #pragma unroll
      for (int ni = 0; ni < 4; ++ni)
        acc[mi][ni] = __builtin_amdgcn_mfma_f32_16x16x32_f16(af[mi], bfr[ni], acc[mi][ni], 0, 0, 0);

    if (nxt < 27) {
      half8 o;
      o[0]=(_Float16)va.x; o[1]=(_Float16)va.y; o[2]=(_Float16)va.z; o[3]=(_Float16)va.w;
      o[4]=(_Float16)vb.x; o[5]=(_Float16)vb.y; o[6]=(_Float16)vb.z; o[7]=(_Float16)vb.w;
      *(half8*)(lds + (cur ^ 1) * 20480 + aoff) = o;
    }
    __syncthreads();
    cur ^= 1;
  }

  // ---------------- routing ----------------
  const int c = t >> 5;
  const int a = t & 31;
  const float bia = bg[t];

  #pragma unroll 1
  for (int pass = 0; pass < 2; ++pass) {
    // dump rows [pass*32, pass*32+32) of votes into smV (stride 264)
    #pragma unroll
    for (int mh = 0; mh < 2; ++mh) {
      const int mi = pass * 2 + mh;
      #pragma unroll
      for (int ni = 0; ni < 4; ++ni) {
        #pragma unroll
        for (int j = 0; j < 4; ++j) {
          const int rl  = mh * 16 + (lane >> 4) * 4 + j;        // 0..31
          const int col = w * 64 + ni * 16 + (lane & 15);
          smV[rl * 264 + col] = acc[mi][ni][j];
        }
      }
    }
    __syncthreads();

    #pragma unroll 1
    for (int pp = 0; pp < 4; ++pp) {
      const int pl = pass * 4 + pp;
      float v[8];
      #pragma unroll
      for (int ic = 0; ic < 8; ++ic) v[ic] = smV[(pp * 8 + ic) * 264 + t];

      float route[8];
      #pragma unroll 1
      for (int it = 0; it < 3; ++it) {
        if (it == 0) {
          #pragma unroll
          for (int ic = 0; ic < 8; ++ic) route[ic] = 0.125f;
        } else {
          #pragma unroll
          for (int ic = 0; ic < 8; ++ic) {
            float mx = -3.4e38f;
            #pragma unroll
            for (int cc = 0; cc < 8; ++cc) mx = fmaxf(mx, smL[ic * 8 + cc]);
            float s = 0.f;
            #pragma unroll
            for (int cc = 0; cc < 8; ++cc) s += __expf(smL[ic * 8 + cc] - mx);
            route[ic] = __expf(smL[ic * 8 + c] - mx) / s;
          }
        }
        float pre = bia;
        #pragma unroll
        for (int ic = 0; ic < 8; ++ic) pre = fmaf(route[ic], v[ic], pre);

        float ns = red32(pre * pre);
        const float nrm = sqrtf(ns);
        const float act = pre * (nrm / (1.0f + ns));

        if (it == 2) {
          outg[(rbase + pl) * 256 + t] = act;
        } else {
          float d[8];
          #pragma unroll
          for (int ic = 0; ic < 8; ++ic) d[ic] = red32(v[ic] * act);
          __syncthreads();
          if (a == 0) {
            #pragma unroll
            for (int ic = 0; ic < 8; ++ic)
              smL[ic * 8 + c] = (it == 0) ? d[ic] : smL[ic * 8 + c] + d[ic];
          }
          __syncthreads();
        }
      }
    }
    __syncthreads();
  }
}

// ---------------- fallback: round-1 fp32 kernel (used only if ws too small) ----------------
__global__ __launch_bounds__(256, 3)
void caps_fused(const float* __restrict__ xg, const float* __restrict__ Wg,
                const float* __restrict__ bg, float* __restrict__ outg) {
  __shared__ __align__(16) float sm[10432];
  float* smA = sm;
  float* smB = sm + 2176;
  float* smV = sm;
  float* smL = sm + 10368;

  const int t    = threadIdx.x;
  const int blk  = blockIdx.x;
  const int rbase = blk * 8;
  const int b2   = rbase / SPT;
  const int posb = rbase % SPT;
  const int z  = posb / 576;
  const int y  = (posb % 576) / 24;
  const int x0 = posb % 24;

  const int pix_t = t >> 4;
  const int oc_t  = t & 15;
  const int am    = t >> 2;
  const int acin  = (t & 3) * 8;
  const int a_pl  = am >> 3;
  const int a_n   = b2 * 8 + (am & 7);
  const int a_bin = a_n & 1;
  const int a_icin = a_n >> 1;

  float acc[4][16];
  #pragma unroll
  for (int i = 0; i < 4; ++i)
    #pragma unroll
    for (int j = 0; j < 16; ++j) acc[i][j] = 0.f;

  #pragma unroll 1
  for (int tap = 0; tap < 27; ++tap) {
    const int dz = tap / 9, dy = (tap % 9) / 3, dx = tap % 3;
    const int zz = z + dz - 1;
    const int yy = y + dy - 1;
    const int xx = x0 + a_pl + dx - 1;

    float4 va = {0.f, 0.f, 0.f, 0.f}, vb = {0.f, 0.f, 0.f, 0.f};
    if ((unsigned)zz < 24u && (unsigned)yy < 24u && (unsigned)xx < 24u) {
      const float* src = xg + ((((a_bin * 24 + zz) * 24 + yy) * 24 + xx) * 8 + a_icin) * 32 + acin;
      va = *(const float4*)src;
      vb = *(const float4*)(src + 4);
    }
    float4 wv[8];
    const float* wsrc = Wg + tap * 8192 + t * 4;
    #pragma unroll
    for (int k = 0; k < 8; ++k) wv[k] = *(const float4*)(wsrc + k * 1024);

    __syncthreads();
    smA[(acin + 0) * 68 + am] = va.x;
    smA[(acin + 1) * 68 + am] = va.y;
    smA[(acin + 2) * 68 + am] = va.z;
    smA[(acin + 3) * 68 + am] = va.w;
    smA[(acin + 4) * 68 + am] = vb.x;
    smA[(acin + 5) * 68 + am] = vb.y;
    smA[(acin + 6) * 68 + am] = vb.z;
    smA[(acin + 7) * 68 + am] = vb.w;
    #pragma unroll
    for (int k = 0; k < 8; ++k) *(float4*)&smB[k * 1024 + t * 4] = wv[k];
    __syncthreads();

    #pragma unroll 8
    for (int cin = 0; cin < 32; ++cin) {
      const float4 a4  = *(const float4*)&smA[cin * 68 + pix_t * 4];
      const float4 b0  = *(const float4*)&smB[cin * 256 + oc_t * 4];
      const float4 b1  = *(const float4*)&smB[cin * 256 + oc_t * 4 + 64];
      const float4 b2v = *(const float4*)&smB[cin * 256 + oc_t * 4 + 128];
      const float4 b3v = *(const float4*)&smB[cin * 256 + oc_t * 4 + 192];
      const float ar[4] = {a4.x, a4.y, a4.z, a4.w};
      #pragma unroll
      for (int i = 0; i < 4; ++i) {
        acc[i][0]  = fmaf(ar[i], b0.x,  acc[i][0]);
        acc[i][1]  = fmaf(ar[i], b0.y,  acc[i][1]);
        acc[i][2]  = fmaf(ar[i], b0.z,  acc[i][2]);
        acc[i][3]  = fmaf(ar[i], b0.w,  acc[i][3]);
        acc[i][4]  = fmaf(ar[i], b1.x,  acc[i][4]);
        acc[i][5]  = fmaf(ar[i], b1.y,  acc[i][5]);
        acc[i][6]  = fmaf(ar[i], b1.z,  acc[i][6]);
        acc[i][7]  = fmaf(ar[i], b1.w,  acc[i][7]);
        acc[i][8]  = fmaf(ar[i], b2v.x, acc[i][8]);
        acc[i][9]  = fmaf(ar[i], b2v.y, acc[i][9]);
        acc[i][10] = fmaf(ar[i], b2v.z, acc[i][10]);
        acc[i][11] = fmaf(ar[i], b2v.w, acc[i][11]);
        acc[i][12] = fmaf(ar[i], b3v.x, acc[i][12]);
        acc[i][13] = fmaf(ar[i], b3v.y, acc[i][13]);
        acc[i][14] = fmaf(ar[i], b3v.z, acc[i][14]);
        acc[i][15] = fmaf(ar[i], b3v.w, acc[i][15]);
      }
    }
  }
  __syncthreads();

  const int c = t >> 5;
  const int a = t & 31;
  const float bia = bg[t];

  #pragma unroll 1
  for (int pass = 0; pass < 2; ++pass) {
    if ((pix_t >> 3) == pass) {
      const int rl = (pix_t & 7) * 4;
      #pragma unroll
      for (int i = 0; i < 4; ++i) {
        #pragma unroll
        for (int jj = 0; jj < 4; ++jj) {
          float4 v4 = {acc[i][jj * 4 + 0], acc[i][jj * 4 + 1],
                       acc[i][jj * 4 + 2], acc[i][jj * 4 + 3]};
          *(float4*)&smV[(rl + i) * 256 + oc_t * 4 + jj * 64] = v4;
        }
      }
    }
    __syncthreads();

    #pragma unroll 1
    for (int pp = 0; pp < 4; ++pp) {
      const int pl = pass * 4 + pp;
      float v[8];
      #pragma unroll
      for (int ic = 0; ic < 8; ++ic) v[ic] = smV[(pp * 8 + ic) * 256 + t];

      float route[8];
      #pragma unroll 1
      for (int it = 0; it < 3; ++it) {
        if (it == 0) {
          #pragma unroll
          for (int ic = 0; ic < 8; ++ic) route[ic] = 0.125f;
        } else {
          #pragma unroll
          for (int ic = 0; ic < 8; ++ic) {
            float mx = -3.4e38f;
            #pragma unroll
            for (int cc = 0; cc < 8; ++cc) mx = fmaxf(mx, smL[ic * 8 + cc]);
            float s = 0.f;
            #pragma unroll
            for (int cc = 0; cc < 8; ++cc) s += __expf(smL[ic * 8 + cc] - mx);
            route[ic] = __expf(smL[ic * 8 + c] - mx) / s;
          }
        }
        float pre = bia;
        #pragma unroll
        for (int ic = 0; ic < 8; ++ic) pre = fmaf(route[ic], v[ic], pre);

        float ns = red32(pre * pre);
        const float nrm = sqrtf(ns);
        const float act = pre * (nrm / (1.0f + ns));

        if (it == 2) {
          outg[(rbase + pl) * 256 + t] = act;
        } else {
          float d[8];
          #pragma unroll
          for (int ic = 0; ic < 8; ++ic) d[ic] = red32(v[ic] * act);
          __syncthreads();
          if (a == 0) {
            #pragma unroll
            for (int ic = 0; ic < 8; ++ic)
              smL[ic * 8 + c] = (it == 0) ? d[ic] : smL[ic * 8 + c] + d[ic];
          }
          __syncthreads();
        }
      }
    }
    __syncthreads();
  }
}

extern "C" void kernel_launch(void* const* d_in, const int* in_sizes, int n_in,
                              void* d_out, int out_size, void* d_ws, size_t ws_size,
                              hipStream_t stream) {
  const float* x = (const float*)d_in[0];
  const float* W = (const float*)d_in[1];
  const float* b = (const float*)d_in[2];
  float* out = (float*)d_out;
  (void)in_sizes; (void)n_in; (void)out_size;

  if (ws_size >= 27u * 8192u * sizeof(_Float16)) {
    _Float16* Wh = (_Float16*)d_ws;
    prep_W<<<dim3(27), dim3(256), 0, stream>>>(W, Wh);
    caps_mfma<<<dim3(3456), dim3(256), 0, stream>>>(x, Wh, b, out);
  } else {
    caps_fused<<<dim3(3456), dim3(256), 0, stream>>>(x, W, b, out);
  }
}

// Round 4
// 451.044 us; speedup vs baseline: 3.5447x; 2.1586x over previous
//
#include <hip/hip_runtime.h>
#include <math.h>

// Conv3DCapsuleLayer: fp16-MFMA implicit-GEMM conv3d + fused 3-iter dynamic routing.
// input_tensor (2,24,24,24,8,32) f32 | W (3,3,3,32,256) f32 | b (1,1,1,8,32) f32
// out = activation (2,24,24,24,8,32) f32
//
// Conv rows n=0..15 map to input (b_in = n&1, ic_in = n>>1)
// Routing votes[b2][ic2] = conv row n = b2*8 + ic2
//
// Round-4 structure: per block (8 x-positions, 64 GEMM rows x 256 cols):
//   for dz in 0..2: stage x-strip (3dy x 10xslot x 8ic x 32cin fp16, 72B rows)
//   into double-buffered LDS; compute 9 taps (dy,dx) off the strip; ONE barrier
//   per round. B (Wh, 432KB L2-resident) read per tap directly global->VGPR
//   (fragment-linear, 1KB/wave contiguous) — no global_load_lds, no per-tap
//   barrier, no vmcnt(0) drains between taps. XCD-chunked block swizzle.

#define SPT 13824   // 24*24*24

typedef __attribute__((ext_vector_type(8))) _Float16 half8;
typedef __attribute__((ext_vector_type(4))) float f32x4;

__device__ __forceinline__ float red32(float v) {
  v += __shfl_xor(v, 16);
  v += __shfl_xor(v, 8);
  v += __shfl_xor(v, 4);
  v += __shfl_xor(v, 2);
  v += __shfl_xor(v, 1);
  return v;
}

// W (3,3,3,32,256) fp32 -> Wh[tap][cb(16)][slot(64)][8] fp16, slot = kg*16+nr:
// element (k = kg*8+j, n = cb*16+nr). This is exactly the MFMA B-fragment order.
__global__ void prep_W(const float* __restrict__ W, _Float16* __restrict__ Wh) {
  const int tap = blockIdx.x;
  #pragma unroll
  for (int rep = 0; rep < 4; ++rep) {
    const int idx = rep * 256 + threadIdx.x;   // 0..1023
    const int cb = idx >> 6;
    const int kg = (idx >> 4) & 3;
    const int nr = idx & 15;
    const int n  = cb * 16 + nr;
    half8 o;
    #pragma unroll
    for (int j = 0; j < 8; ++j)
      o[j] = (_Float16)W[(tap * 32 + kg * 8 + j) * 256 + n];
    *(half8*)(Wh + tap * 8192 + idx * 8) = o;
  }
}

__global__ __launch_bounds__(256, 3)
void caps_mfma2(const float* __restrict__ xg, const _Float16* __restrict__ Wh,
                const float* __restrict__ bg, float* __restrict__ outg) {
  // LDS: strip buf0 at 0, buf1 at 17280 (each 240 rows x 72B = 17280B)
  // Routing aliases: smV f32 [32][264] at 0 (33792B), smL at 34560 (256B)
  __shared__ __align__(16) unsigned char lds[34816];
  float* smV = (float*)lds;
  float* smL = (float*)(lds + 34560);

  const int t    = threadIdx.x;
  const int lane = t & 63;
  const int w    = t >> 6;
  // XCD-chunked swizzle: 3456 = 8 XCDs x 432 contiguous blocks
  const int wg   = (blockIdx.x & 7) * 432 + (blockIdx.x >> 3);
  const int rbase = wg * 8;
  const int b2   = rbase / SPT;
  const int posb = rbase % SPT;
  const int z  = posb / 576;
  const int y  = (posb % 576) / 24;
  const int x0 = posb % 24;

  // ---- strip staging mapping (threads 0..239) ----
  const bool stager = t < 240;
  const int sdy  = t / 80;           // 0..2
  const int srem = t % 80;
  const int sxs  = srem >> 3;        // x-slot 0..9
  const int sic  = srem & 7;         // GEMM-row ic
  const int sn   = b2 * 8 + sic;
  const int sbin = sn & 1;
  const int sicin = sn >> 1;
  const int syy  = y + sdy - 1;
  const int sxx  = x0 + sxs - 1;
  const int sR   = (sdy * 10 + sxs) * 8 + sic;      // strip row
  const bool syx_ok = (unsigned)syy < 24u && (unsigned)sxx < 24u;
  const float* sbase = xg + (((sbin * 24) * 24 + (syx_ok ? syy : 0)) * 24 + (syx_ok ? sxx : 0)) * 256 + sicin * 32;

  // ---- A-fragment lane bases (bytes within a strip buffer) ----
  // af[mi] lane l: row R = ((mi*2 + ((l&15)>>3)) * 8 + (l&7)), kg = l>>4
  // addr = R*72 + kg*16 + (dy*10+dx)*576
  const int lm = lane & 15;
  int abase[4];
  #pragma unroll
  for (int mi = 0; mi < 4; ++mi)
    abase[mi] = ((mi * 2 + (lm >> 3)) * 8 + (lane & 7)) * 72 + (lane >> 4) * 16;

  // B fragment base: Wh + tap*8192 + (w*4+ni)*512 + lane*8  (halves)
  const _Float16* bbase = Wh + w * 2048 + lane * 8;

  f32x4 acc[4][4];
  #pragma unroll
  for (int mi = 0; mi < 4; ++mi)
    #pragma unroll
    for (int ni = 0; ni < 4; ++ni) acc[mi][ni] = (f32x4){0.f, 0.f, 0.f, 0.f};

  // ---- prologue: stage strip for dz=0 (zz = z-1) into buf0 ----
  {
    const int zz = z - 1;
    const bool val = (unsigned)zz < 24u && syx_ok;
    const float* src = sbase + (zz >= 0 ? zz : 0) * 24 * 24 * 256;
    half8 h[4];
    #pragma unroll
    for (int j = 0; j < 4; ++j) {
      float4 qa = val ? *(const float4*)(src + j * 8)     : (float4){0,0,0,0};
      float4 qb = val ? *(const float4*)(src + j * 8 + 4) : (float4){0,0,0,0};
      half8 hh;
      hh[0]=(_Float16)qa.x; hh[1]=(_Float16)qa.y; hh[2]=(_Float16)qa.z; hh[3]=(_Float16)qa.w;
      hh[4]=(_Float16)qb.x; hh[5]=(_Float16)qb.y; hh[6]=(_Float16)qb.z; hh[7]=(_Float16)qb.w;
      h[j] = hh;
    }
    if (stager) {
      unsigned char* dst = lds + sR * 72;
      #pragma unroll
      for (int j = 0; j < 4; ++j) *(half8*)(dst + j * 16) = h[j];
    }
  }
  __syncthreads();

  #pragma unroll 1
  for (int dz = 0; dz < 3; ++dz) {
    // ---- issue + convert next strip (dz+1 -> zz = z+dz) early ----
    half8 h[4];
    const bool have = dz < 2;
    {
      const int zz = z + dz;
      const bool val = have && (unsigned)zz < 24u && syx_ok;
      const float* src = sbase + zz * 24 * 24 * 256;
      #pragma unroll
      for (int j = 0; j < 4; ++j) {
        float4 qa = val ? *(const float4*)(src + j * 8)     : (float4){0,0,0,0};
        float4 qb = val ? *(const float4*)(src + j * 8 + 4) : (float4){0,0,0,0};
        half8 hh;
        hh[0]=(_Float16)qa.x; hh[1]=(_Float16)qa.y; hh[2]=(_Float16)qa.z; hh[3]=(_Float16)qa.w;
        hh[4]=(_Float16)qb.x; hh[5]=(_Float16)qb.y; hh[6]=(_Float16)qb.z; hh[7]=(_Float16)qb.w;
        h[j] = hh;
      }
    }

    const unsigned char* sb = lds + (dz & 1) * 17280;
    #pragma unroll 1
    for (int dy = 0; dy < 3; ++dy) {
      const _Float16* bt = bbase + (dz * 9 + dy * 3) * 8192;
      // one-dx-lookahead B register double buffer (named sets, static idx)
      half8 bA0, bA1, bA2, bA3, bB0, bB1, bB2, bB3;
      bA0 = *(const half8*)(bt + 0 * 512);
      bA1 = *(const half8*)(bt + 1 * 512);
      bA2 = *(const half8*)(bt + 2 * 512);
      bA3 = *(const half8*)(bt + 3 * 512);

      // ---- dx = 0 (use A-set, prefetch B-set) ----
      bB0 = *(const half8*)(bt + 8192 + 0 * 512);
      bB1 = *(const half8*)(bt + 8192 + 1 * 512);
      bB2 = *(const half8*)(bt + 8192 + 2 * 512);
      bB3 = *(const half8*)(bt + 8192 + 3 * 512);
      {
        const int imm = dy * 5760;   // (dy*10+0)*576
        half8 af[4];
        #pragma unroll
        for (int mi = 0; mi < 4; ++mi) af[mi] = *(const half8*)(sb + abase[mi] + imm);
        #pragma unroll
        for (int mi = 0; mi < 4; ++mi) {
          acc[mi][0] = __builtin_amdgcn_mfma_f32_16x16x32_f16(af[mi], bA0, acc[mi][0], 0, 0, 0);
          acc[mi][1] = __builtin_amdgcn_mfma_f32_16x16x32_f16(af[mi], bA1, acc[mi][1], 0, 0, 0);
          acc[mi][2] = __builtin_amdgcn_mfma_f32_16x16x32_f16(af[mi], bA2, acc[mi][2], 0, 0, 0);
          acc[mi][3] = __builtin_amdgcn_mfma_f32_16x16x32_f16(af[mi], bA3, acc[mi][3], 0, 0, 0);
        }
      }
      // ---- dx = 1 (use B-set, prefetch A-set for dx=2) ----
      bA0 = *(const half8*)(bt + 16384 + 0 * 512);
      bA1 = *(const half8*)(bt + 16384 + 1 * 512);
      bA2 = *(const half8*)(bt + 16384 + 2 * 512);
      bA3 = *(const half8*)(bt + 16384 + 3 * 512);
      {
        const int imm = dy * 5760 + 576;
        half8 af[4];
        #pragma unroll
        for (int mi = 0; mi < 4; ++mi) af[mi] = *(const half8*)(sb + abase[mi] + imm);
        #pragma unroll
        for (int mi = 0; mi < 4; ++mi) {
          acc[mi][0] = __builtin_amdgcn_mfma_f32_16x16x32_f16(af[mi], bB0, acc[mi][0], 0, 0, 0);
          acc[mi][1] = __builtin_amdgcn_mfma_f32_16x16x32_f16(af[mi], bB1, acc[mi][1], 0, 0, 0);
          acc[mi][2] = __builtin_amdgcn_mfma_f32_16x16x32_f16(af[mi], bB2, acc[mi][2], 0, 0, 0);
          acc[mi][3] = __builtin_amdgcn_mfma_f32_16x16x32_f16(af[mi], bB3, acc[mi][3], 0, 0, 0);
        }
      }
      // ---- dx = 2 (use A-set) ----
      {
        const int imm = dy * 5760 + 1152;
        half8 af[4];
        #pragma unroll
        for (int mi = 0; mi < 4; ++mi) af[mi] = *(const half8*)(sb + abase[mi] + imm);
        #pragma unroll
        for (int mi = 0; mi < 4; ++mi) {
          acc[mi][0] = __builtin_amdgcn_mfma_f32_16x16x32_f16(af[mi], bA0, acc[mi][0], 0, 0, 0);
          acc[mi][1] = __builtin_amdgcn_mfma_f32_16x16x32_f16(af[mi], bA1, acc[mi][1], 0, 0, 0);
          acc[mi][2] = __builtin_amdgcn_mfma_f32_16x16x32_f16(af[mi], bA2, acc[mi][2], 0, 0, 0);
          acc[mi][3] = __builtin_amdgcn_mfma_f32_16x16x32_f16(af[mi], bA3, acc[mi][3], 0, 0, 0);
        }
      }
    }

    // write next strip into the other buffer; one barrier per round
    if (have && stager) {
      unsigned char* dst = lds + ((dz + 1) & 1) * 17280 + sR * 72;
      #pragma unroll
      for (int j = 0; j < 4; ++j) *(half8*)(dst + j * 16) = h[j];
    }
    __syncthreads();
  }

  // ---------------- routing ----------------
  const int c = t >> 5;
  const int a = t & 31;
  const float bia = bg[t];

  #pragma unroll 1
  for (int pass = 0; pass < 2; ++pass) {
    // dump rows [pass*32, pass*32+32) of votes into smV (stride 264)
    #pragma unroll
    for (int mh = 0; mh < 2; ++mh) {
      const int mi = pass * 2 + mh;
      #pragma unroll
      for (int ni = 0; ni < 4; ++ni) {
        #pragma unroll
        for (int j = 0; j < 4; ++j) {
          const int rl  = mh * 16 + (lane >> 4) * 4 + j;        // 0..31
          const int col = w * 64 + ni * 16 + (lane & 15);
          smV[rl * 264 + col] = acc[mi][ni][j];
        }
      }
    }
    __syncthreads();

    #pragma unroll 1
    for (int pp = 0; pp < 4; ++pp) {
      const int pl = pass * 4 + pp;
      float v[8];
      #pragma unroll
      for (int ic = 0; ic < 8; ++ic) v[ic] = smV[(pp * 8 + ic) * 264 + t];

      float route[8];
      #pragma unroll 1
      for (int it = 0; it < 3; ++it) {
        if (it == 0) {
          #pragma unroll
          for (int ic = 0; ic < 8; ++ic) route[ic] = 0.125f;
        } else {
          #pragma unroll
          for (int ic = 0; ic < 8; ++ic) {
            float mx = -3.4e38f;
            #pragma unroll
            for (int cc = 0; cc < 8; ++cc) mx = fmaxf(mx, smL[ic * 8 + cc]);
            float s = 0.f;
            #pragma unroll
            for (int cc = 0; cc < 8; ++cc) s += __expf(smL[ic * 8 + cc] - mx);
            route[ic] = __expf(smL[ic * 8 + c] - mx) / s;
          }
        }
        float pre = bia;
        #pragma unroll
        for (int ic = 0; ic < 8; ++ic) pre = fmaf(route[ic], v[ic], pre);

        float ns = red32(pre * pre);
        const float nrm = sqrtf(ns);
        const float act = pre * (nrm / (1.0f + ns));

        if (it == 2) {
          outg[(rbase + pl) * 256 + t] = act;
        } else {
          float d[8];
          #pragma unroll
          for (int ic = 0; ic < 8; ++ic) d[ic] = red32(v[ic] * act);
          __syncthreads();
          if (a == 0) {
            #pragma unroll
            for (int ic = 0; ic < 8; ++ic)
              smL[ic * 8 + c] = (it == 0) ? d[ic] : smL[ic * 8 + c] + d[ic];
          }
          __syncthreads();
        }
      }
    }
    __syncthreads();
  }
}

// ---------------- fallback: fp32 kernel (used only if ws too small) ----------------
__global__ __launch_bounds__(256, 3)
void caps_fused(const float* __restrict__ xg, const float* __restrict__ Wg,
                const float* __restrict__ bg, float* __restrict__ outg) {
  __shared__ __align__(16) float sm[10432];
  float* smA = sm;
  float* smB = sm + 2176;
  float* smV = sm;
  float* smL = sm + 10368;

  const int t    = threadIdx.x;
  const int blk  = blockIdx.x;
  const int rbase = blk * 8;
  const int b2   = rbase / SPT;
  const int posb = rbase % SPT;
  const int z  = posb / 576;
  const int y  = (posb % 576) / 24;
  const int x0 = posb % 24;

  const int pix_t = t >> 4;
  const int oc_t  = t & 15;
  const int am    = t >> 2;
  const int acin  = (t & 3) * 8;
  const int a_pl  = am >> 3;
  const int a_n   = b2 * 8 + (am & 7);
  const int a_bin = a_n & 1;
  const int a_icin = a_n >> 1;

  float acc[4][16];
  #pragma unroll
  for (int i = 0; i < 4; ++i)
    #pragma unroll
    for (int j = 0; j < 16; ++j) acc[i][j] = 0.f;

  #pragma unroll 1
  for (int tap = 0; tap < 27; ++tap) {
    const int dz = tap / 9, dy = (tap % 9) / 3, dx = tap % 3;
    const int zz = z + dz - 1;
    const int yy = y + dy - 1;
    const int xx = x0 + a_pl + dx - 1;

    float4 va = {0.f, 0.f, 0.f, 0.f}, vb = {0.f, 0.f, 0.f, 0.f};
    if ((unsigned)zz < 24u && (unsigned)yy < 24u && (unsigned)xx < 24u) {
      const float* src = xg + ((((a_bin * 24 + zz) * 24 + yy) * 24 + xx) * 8 + a_icin) * 32 + acin;
      va = *(const float4*)src;
      vb = *(const float4*)(src + 4);
    }
    float4 wv[8];
    const float* wsrc = Wg + tap * 8192 + t * 4;
    #pragma unroll
    for (int k = 0; k < 8; ++k) wv[k] = *(const float4*)(wsrc + k * 1024);

    __syncthreads();
    smA[(acin + 0) * 68 + am] = va.x;
    smA[(acin + 1) * 68 + am] = va.y;
    smA[(acin + 2) * 68 + am] = va.z;
    smA[(acin + 3) * 68 + am] = va.w;
    smA[(acin + 4) * 68 + am] = vb.x;
    smA[(acin + 5) * 68 + am] = vb.y;
    smA[(acin + 6) * 68 + am] = vb.z;
    smA[(acin + 7) * 68 + am] = vb.w;
    #pragma unroll
    for (int k = 0; k < 8; ++k) *(float4*)&smB[k * 1024 + t * 4] = wv[k];
    __syncthreads();

    #pragma unroll 8
    for (int cin = 0; cin < 32; ++cin) {
      const float4 a4  = *(const float4*)&smA[cin * 68 + pix_t * 4];
      const float4 b0  = *(const float4*)&smB[cin * 256 + oc_t * 4];
      const float4 b1  = *(const float4*)&smB[cin * 256 + oc_t * 4 + 64];
      const float4 b2v = *(const float4*)&smB[cin * 256 + oc_t * 4 + 128];
      const float4 b3v = *(const float4*)&smB[cin * 256 + oc_t * 4 + 192];
      const float ar[4] = {a4.x, a4.y, a4.z, a4.w};
      #pragma unroll
      for (int i = 0; i < 4; ++i) {
        acc[i][0]  = fmaf(ar[i], b0.x,  acc[i][0]);
        acc[i][1]  = fmaf(ar[i], b0.y,  acc[i][1]);
        acc[i][2]  = fmaf(ar[i], b0.z,  acc[i][2]);
        acc[i][3]  = fmaf(ar[i], b0.w,  acc[i][3]);
        acc[i][4]  = fmaf(ar[i], b1.x,  acc[i][4]);
        acc[i][5]  = fmaf(ar[i], b1.y,  acc[i][5]);
        acc[i][6]  = fmaf(ar[i], b1.z,  acc[i][6]);
        acc[i][7]  = fmaf(ar[i], b1.w,  acc[i][7]);
        acc[i][8]  = fmaf(ar[i], b2v.x, acc[i][8]);
        acc[i][9]  = fmaf(ar[i], b2v.y, acc[i][9]);
        acc[i][10] = fmaf(ar[i], b2v.z, acc[i][10]);
        acc[i][11] = fmaf(ar[i], b2v.w, acc[i][11]);
        acc[i][12] = fmaf(ar[i], b3v.x, acc[i][12]);
        acc[i][13] = fmaf(ar[i], b3v.y, acc[i][13]);
        acc[i][14] = fmaf(ar[i], b3v.z, acc[i][14]);
        acc[i][15] = fmaf(ar[i], b3v.w, acc[i][15]);
      }
    }
  }
  __syncthreads();

  const int c = t >> 5;
  const int a = t & 31;
  const float bia = bg[t];

  #pragma unroll 1
  for (int pass = 0; pass < 2; ++pass) {
    if ((pix_t >> 3) == pass) {
      const int rl = (pix_t & 7) * 4;
      #pragma unroll
      for (int i = 0; i < 4; ++i) {
        #pragma unroll
        for (int jj = 0; jj < 4; ++jj) {
          float4 v4 = {acc[i][jj * 4 + 0], acc[i][jj * 4 + 1],
                       acc[i][jj * 4 + 2], acc[i][jj * 4 + 3]};
          *(float4*)&smV[(rl + i) * 256 + oc_t * 4 + jj * 64] = v4;
        }
      }
    }
    __syncthreads();

    #pragma unroll 1
    for (int pp = 0; pp < 4; ++pp) {
      const int pl = pass * 4 + pp;
      float v[8];
      #pragma unroll
      for (int ic = 0; ic < 8; ++ic) v[ic] = smV[(pp * 8 + ic) * 256 + t];

      float route[8];
      #pragma unroll 1
      for (int it = 0; it < 3; ++it) {
        if (it == 0) {
          #pragma unroll
          for (int ic = 0; ic < 8; ++ic) route[ic] = 0.125f;
        } else {
          #pragma unroll
          for (int ic = 0; ic < 8; ++ic) {
            float mx = -3.4e38f;
            #pragma unroll
            for (int cc = 0; cc < 8; ++cc) mx = fmaxf(mx, smL[ic * 8 + cc]);
            float s = 0.f;
            #pragma unroll
            for (int cc = 0; cc < 8; ++cc) s += __expf(smL[ic * 8 + cc] - mx);
            route[ic] = __expf(smL[ic * 8 + c] - mx) / s;
          }
        }
        float pre = bia;
        #pragma unroll
        for (int ic = 0; ic < 8; ++ic) pre = fmaf(route[ic], v[ic], pre);

        float ns = red32(pre * pre);
        const float nrm = sqrtf(ns);
        const float act = pre * (nrm / (1.0f + ns));

        if (it == 2) {
          outg[(rbase + pl) * 256 + t] = act;
        } else {
          float d[8];
          #pragma unroll
          for (int ic = 0; ic < 8; ++ic) d[ic] = red32(v[ic] * act);
          __syncthreads();
          if (a == 0) {
            #pragma unroll
            for (int ic = 0; ic < 8; ++ic)
              smL[ic * 8 + c] = (it == 0) ? d[ic] : smL[ic * 8 + c] + d[ic];
          }
          __syncthreads();
        }
      }
    }
    __syncthreads();
  }
}

extern "C" void kernel_launch(void* const* d_in, const int* in_sizes, int n_in,
                              void* d_out, int out_size, void* d_ws, size_t ws_size,
                              hipStream_t stream) {
  const float* x = (const float*)d_in[0];
  const float* W = (const float*)d_in[1];
  const float* b = (const float*)d_in[2];
  float* out = (float*)d_out;
  (void)in_sizes; (void)n_in; (void)out_size;

  if (ws_size >= 27u * 8192u * sizeof(_Float16)) {
    _Float16* Wh = (_Float16*)d_ws;
    prep_W<<<dim3(27), dim3(256), 0, stream>>>(W, Wh);
    caps_mfma2<<<dim3(3456), dim3(256), 0, stream>>>(x, Wh, b, out);
  } else {
    caps_fused<<<dim3(3456), dim3(256), 0, stream>>>(x, W, b, out);
  }
}

// Round 8
// 378.675 us; speedup vs baseline: 4.2221x; 1.1911x over previous
//
#include <hip/hip_runtime.h>
#include <math.h>

// Conv3DCapsuleLayer: fp16-MFMA implicit-GEMM conv3d + fused 3-iter dynamic routing.
// input_tensor (2,24,24,24,8,32) f32 | W (3,3,3,32,256) f32 | b (1,1,1,8,32) f32
// out = activation (2,24,24,24,8,32) f32
//
// Conv rows n=0..15 map to input (b_in = n&1, ic_in = n>>1)
// Routing votes[b2][ic2] = conv row n = b2*8 + ic2
//
// Round-8: GEMM verbatim round 4 (verified). Routing is wave-parallel (wave w
// owns position pass*4+w) but built ONLY from primitives verified in passing
// rounds: lane = (ch = l>>5, al = l&31) owns atom al of capsules c = 2q+ch.
//  - atom reductions: shfl_xor 16,8,4,2,1 within a 32-lane half (= round-4 red32)
//  - capsule softmax: per-wave 8x8 logits table in LDS, write-under-if +
//    __syncthreads + broadcast read (= round-4 smL protocol)
//  - NO cross-half shuffles, NO 8-lane-group shuffles (unique to failed r5-r7).

#define SPT 13824   // 24*24*24

typedef __attribute__((ext_vector_type(8))) _Float16 half8;
typedef __attribute__((ext_vector_type(4))) float f32x4;

// reduce over a 32-lane half (masks 16,8,4,2,1) — verified rounds 1-4
__device__ __forceinline__ float redhalf(float v) {
  v += __shfl_xor(v, 16);
  v += __shfl_xor(v, 8);
  v += __shfl_xor(v, 4);
  v += __shfl_xor(v, 2);
  v += __shfl_xor(v, 1);
  return v;
}

// W (3,3,3,32,256) fp32 -> Wh[tap][cb(16)][slot(64)][8] fp16, slot = kg*16+nr:
// element (k = kg*8+j, n = cb*16+nr). This is exactly the MFMA B-fragment order.
__global__ void prep_W(const float* __restrict__ W, _Float16* __restrict__ Wh) {
  const int tap = blockIdx.x;
  #pragma unroll
  for (int rep = 0; rep < 4; ++rep) {
    const int idx = rep * 256 + threadIdx.x;   // 0..1023
    const int cb = idx >> 6;
    const int kg = (idx >> 4) & 3;
    const int nr = idx & 15;
    const int n  = cb * 16 + nr;
    half8 o;
    #pragma unroll
    for (int j = 0; j < 8; ++j)
      o[j] = (_Float16)W[(tap * 32 + kg * 8 + j) * 256 + n];
    *(half8*)(Wh + tap * 8192 + idx * 8) = o;
  }
}

__global__ __launch_bounds__(256, 3)
void caps_mfma6(const float* __restrict__ xg, const _Float16* __restrict__ Wh,
                const float* __restrict__ bg, float* __restrict__ outg) {
  // LDS: strip buf0 at 0, buf1 at 17280 (each 17280B); routing aliases:
  // smV f32 [32][264] at 0 (33792B), smLw 4 waves x 64 f32 at 33792 (1024B)
  __shared__ __align__(16) unsigned char lds[34816];
  float* smV = (float*)lds;

  const int t    = threadIdx.x;
  const int lane = t & 63;
  const int w    = t >> 6;
  // XCD-chunked swizzle: 3456 = 8 XCDs x 432 contiguous blocks
  const int wg   = (blockIdx.x & 7) * 432 + (blockIdx.x >> 3);
  const int rbase = wg * 8;
  const int b2   = rbase / SPT;
  const int posb = rbase % SPT;
  const int z  = posb / 576;
  const int y  = (posb % 576) / 24;
  const int x0 = posb % 24;

  // ---- strip staging mapping (threads 0..239) ----
  const bool stager = t < 240;
  const int sdy  = t / 80;           // 0..2
  const int srem = t % 80;
  const int sxs  = srem >> 3;        // x-slot 0..9
  const int sic  = srem & 7;         // GEMM-row ic
  const int sn   = b2 * 8 + sic;
  const int sbin = sn & 1;
  const int sicin = sn >> 1;
  const int syy  = y + sdy - 1;
  const int sxx  = x0 + sxs - 1;
  const int sR   = (sdy * 10 + sxs) * 8 + sic;      // strip row
  const bool syx_ok = (unsigned)syy < 24u && (unsigned)sxx < 24u;
  const float* sbase = xg + (((sbin * 24) * 24 + (syx_ok ? syy : 0)) * 24 + (syx_ok ? sxx : 0)) * 256 + sicin * 32;

  // ---- A-fragment lane bases (bytes within a strip buffer) ----
  const int lm = lane & 15;
  int abase[4];
  #pragma unroll
  for (int mi = 0; mi < 4; ++mi)
    abase[mi] = ((mi * 2 + (lm >> 3)) * 8 + (lane & 7)) * 72 + (lane >> 4) * 16;

  // B fragment base: Wh + tap*8192 + (w*4+ni)*512 + lane*8  (halves)
  const _Float16* bbase = Wh + w * 2048 + lane * 8;

  f32x4 acc[4][4];
  #pragma unroll
  for (int mi = 0; mi < 4; ++mi)
    #pragma unroll
    for (int ni = 0; ni < 4; ++ni) acc[mi][ni] = (f32x4){0.f, 0.f, 0.f, 0.f};

  // ---- prologue: stage strip for dz=0 (zz = z-1) into buf0 ----
  {
    const int zz = z - 1;
    const bool val = (unsigned)zz < 24u && syx_ok;
    const float* src = sbase + (zz >= 0 ? zz : 0) * 24 * 24 * 256;
    half8 h[4];
    #pragma unroll
    for (int j = 0; j < 4; ++j) {
      float4 qa = val ? *(const float4*)(src + j * 8)     : (float4){0,0,0,0};
      float4 qb = val ? *(const float4*)(src + j * 8 + 4) : (float4){0,0,0,0};
      half8 hh;
      hh[0]=(_Float16)qa.x; hh[1]=(_Float16)qa.y; hh[2]=(_Float16)qa.z; hh[3]=(_Float16)qa.w;
      hh[4]=(_Float16)qb.x; hh[5]=(_Float16)qb.y; hh[6]=(_Float16)qb.z; hh[7]=(_Float16)qb.w;
      h[j] = hh;
    }
    if (stager) {
      unsigned char* dst = lds + sR * 72;
      #pragma unroll
      for (int j = 0; j < 4; ++j) *(half8*)(dst + j * 16) = h[j];
    }
  }
  __syncthreads();

  #pragma unroll 1
  for (int dz = 0; dz < 3; ++dz) {
    // ---- issue + convert next strip (zz = z+dz) early ----
    half8 h[4];
    const bool have = dz < 2;
    {
      const int zz = z + dz;
      const bool val = have && (unsigned)zz < 24u && syx_ok;
      const float* src = sbase + zz * 24 * 24 * 256;
      #pragma unroll
      for (int j = 0; j < 4; ++j) {
        float4 qa = val ? *(const float4*)(src + j * 8)     : (float4){0,0,0,0};
        float4 qb = val ? *(const float4*)(src + j * 8 + 4) : (float4){0,0,0,0};
        half8 hh;
        hh[0]=(_Float16)qa.x; hh[1]=(_Float16)qa.y; hh[2]=(_Float16)qa.z; hh[3]=(_Float16)qa.w;
        hh[4]=(_Float16)qb.x; hh[5]=(_Float16)qb.y; hh[6]=(_Float16)qb.z; hh[7]=(_Float16)qb.w;
        h[j] = hh;
      }
    }

    const unsigned char* sb = lds + (dz & 1) * 17280;
    #pragma unroll 1
    for (int dy = 0; dy < 3; ++dy) {
      const _Float16* bt = bbase + (dz * 9 + dy * 3) * 8192;
      half8 bA0, bA1, bA2, bA3, bB0, bB1, bB2, bB3;
      bA0 = *(const half8*)(bt + 0 * 512);
      bA1 = *(const half8*)(bt + 1 * 512);
      bA2 = *(const half8*)(bt + 2 * 512);
      bA3 = *(const half8*)(bt + 3 * 512);

      // ---- dx = 0 (use A-set, prefetch B-set) ----
      bB0 = *(const half8*)(bt + 8192 + 0 * 512);
      bB1 = *(const half8*)(bt + 8192 + 1 * 512);
      bB2 = *(const half8*)(bt + 8192 + 2 * 512);
      bB3 = *(const half8*)(bt + 8192 + 3 * 512);
      {
        const int imm = dy * 5760;
        half8 af[4];
        #pragma unroll
        for (int mi = 0; mi < 4; ++mi) af[mi] = *(const half8*)(sb + abase[mi] + imm);
        #pragma unroll
        for (int mi = 0; mi < 4; ++mi) {
          acc[mi][0] = __builtin_amdgcn_mfma_f32_16x16x32_f16(af[mi], bA0, acc[mi][0], 0, 0, 0);
          acc[mi][1] = __builtin_amdgcn_mfma_f32_16x16x32_f16(af[mi], bA1, acc[mi][1], 0, 0, 0);
          acc[mi][2] = __builtin_amdgcn_mfma_f32_16x16x32_f16(af[mi], bA2, acc[mi][2], 0, 0, 0);
          acc[mi][3] = __builtin_amdgcn_mfma_f32_16x16x32_f16(af[mi], bA3, acc[mi][3], 0, 0, 0);
        }
      }
      // ---- dx = 1 (use B-set, prefetch A-set for dx=2) ----
      bA0 = *(const half8*)(bt + 16384 + 0 * 512);
      bA1 = *(const half8*)(bt + 16384 + 1 * 512);
      bA2 = *(const half8*)(bt + 16384 + 2 * 512);
      bA3 = *(const half8*)(bt + 16384 + 3 * 512);
      {
        const int imm = dy * 5760 + 576;
        half8 af[4];
        #pragma unroll
        for (int mi = 0; mi < 4; ++mi) af[mi] = *(const half8*)(sb + abase[mi] + imm);
        #pragma unroll
        for (int mi = 0; mi < 4; ++mi) {
          acc[mi][0] = __builtin_amdgcn_mfma_f32_16x16x32_f16(af[mi], bB0, acc[mi][0], 0, 0, 0);
          acc[mi][1] = __builtin_amdgcn_mfma_f32_16x16x32_f16(af[mi], bB1, acc[mi][1], 0, 0, 0);
          acc[mi][2] = __builtin_amdgcn_mfma_f32_16x16x32_f16(af[mi], bB2, acc[mi][2], 0, 0, 0);
          acc[mi][3] = __builtin_amdgcn_mfma_f32_16x16x32_f16(af[mi], bB3, acc[mi][3], 0, 0, 0);
        }
      }
      // ---- dx = 2 (use A-set) ----
      {
        const int imm = dy * 5760 + 1152;
        half8 af[4];
        #pragma unroll
        for (int mi = 0; mi < 4; ++mi) af[mi] = *(const half8*)(sb + abase[mi] + imm);
        #pragma unroll
        for (int mi = 0; mi < 4; ++mi) {
          acc[mi][0] = __builtin_amdgcn_mfma_f32_16x16x32_f16(af[mi], bA0, acc[mi][0], 0, 0, 0);
          acc[mi][1] = __builtin_amdgcn_mfma_f32_16x16x32_f16(af[mi], bA1, acc[mi][1], 0, 0, 0);
          acc[mi][2] = __builtin_amdgcn_mfma_f32_16x16x32_f16(af[mi], bA2, acc[mi][2], 0, 0, 0);
          acc[mi][3] = __builtin_amdgcn_mfma_f32_16x16x32_f16(af[mi], bA3, acc[mi][3], 0, 0, 0);
        }
      }
    }

    if (have && stager) {
      unsigned char* dst = lds + ((dz + 1) & 1) * 17280 + sR * 72;
      #pragma unroll
      for (int j = 0; j < 4; ++j) *(half8*)(dst + j * 16) = h[j];
    }
    __syncthreads();
  }

  // ---------------- routing (wave-parallel, verified primitives only) ----------------
  // lane = (ch = l>>5, al = l&31). Wave w routes position pl = pass*4 + w.
  // Lane owns atom al of capsules c = 2q+ch (q=0..3).
  const int ch = lane >> 5;
  const int al = lane & 31;
  float* smLw = (float*)(lds + 33792) + w * 64;   // per-wave [ic][c] logits

  float bia[4];
  #pragma unroll
  for (int q = 0; q < 4; ++q) bia[q] = bg[(2 * q + ch) * 32 + al];

  #pragma unroll 1
  for (int pass = 0; pass < 2; ++pass) {
    // dump rows [pass*32, pass*32+32) of votes — verbatim round-4 dump
    #pragma unroll
    for (int mh = 0; mh < 2; ++mh) {
      const int mi = pass * 2 + mh;
      #pragma unroll
      for (int ni = 0; ni < 4; ++ni) {
        #pragma unroll
        for (int j = 0; j < 4; ++j) {
          const int rl  = mh * 16 + (lane >> 4) * 4 + j;        // 0..31
          const int col = w * 64 + ni * 16 + (lane & 15);
          smV[rl * 264 + col] = acc[mi][ni][j];
        }
      }
    }
    __syncthreads();

    // this wave's position: v[ic][q] = votes[ic][capsule 2q+ch][atom al]
    float v[8][4];
    #pragma unroll
    for (int ic = 0; ic < 8; ++ic)
      #pragma unroll
      for (int q = 0; q < 4; ++q)
        v[ic][q] = smV[(w * 8 + ic) * 264 + (2 * q + ch) * 32 + al];

    #pragma unroll 1
    for (int it = 0; it < 3; ++it) {
      // preactivate (softmax from per-wave LDS table, round-4 style)
      float pre[4];
      #pragma unroll
      for (int q = 0; q < 4; ++q) pre[q] = bia[q];
      if (it == 0) {
        #pragma unroll
        for (int ic = 0; ic < 8; ++ic)
          #pragma unroll
          for (int q = 0; q < 4; ++q)
            pre[q] = fmaf(0.125f, v[ic][q], pre[q]);
      } else {
        #pragma unroll
        for (int ic = 0; ic < 8; ++ic) {
          float Lv[8];
          #pragma unroll
          for (int cc = 0; cc < 8; ++cc) Lv[cc] = smLw[ic * 8 + cc];
          float mx = Lv[0];
          #pragma unroll
          for (int cc = 1; cc < 8; ++cc) mx = fmaxf(mx, Lv[cc]);
          float e[8];
          float s = 0.f;
          #pragma unroll
          for (int cc = 0; cc < 8; ++cc) { e[cc] = __expf(Lv[cc] - mx); s += e[cc]; }
          const float inv = 1.0f / s;
          #pragma unroll
          for (int q = 0; q < 4; ++q)
            pre[q] = fmaf(e[2 * q + ch] * inv, v[ic][q], pre[q]);
        }
      }

      // squash: norm over atoms (32-lane half reduce, verified primitive)
      float act[4];
      #pragma unroll
      for (int q = 0; q < 4; ++q) {
        float ns = redhalf(pre[q] * pre[q]);
        act[q] = pre[q] * (sqrtf(ns) / (1.0f + ns));
      }

      if (it == 2) {
        const int pl = pass * 4 + w;
        #pragma unroll
        for (int q = 0; q < 4; ++q)
          outg[(rbase + pl) * 256 + (2 * q + ch) * 32 + al] = act[q];
      } else {
        // distances (half-reduce over atoms) -> logits table update
        float d[8][4];
        #pragma unroll
        for (int ic = 0; ic < 8; ++ic)
          #pragma unroll
          for (int q = 0; q < 4; ++q)
            d[ic][q] = redhalf(v[ic][q] * act[q]);
        __syncthreads();   // all softmax reads of smLw done (round-4 protocol)
        if (al == 0) {
          #pragma unroll
          for (int ic = 0; ic < 8; ++ic)
            #pragma unroll
            for (int q = 0; q < 4; ++q) {
              const int cc = 2 * q + ch;
              smLw[ic * 8 + cc] = (it == 0) ? d[ic][q] : smLw[ic * 8 + cc] + d[ic][q];
            }
        }
        __syncthreads();   // logits visible for next iteration
      }
    }
    __syncthreads();       // smV reads done before next pass overwrites
  }
}

// ---------------- fallback: fp32 kernel (used only if ws too small) ----------------
__global__ __launch_bounds__(256, 3)
void caps_fused(const float* __restrict__ xg, const float* __restrict__ Wg,
                const float* __restrict__ bg, float* __restrict__ outg) {
  __shared__ __align__(16) float sm[10432];
  float* smA = sm;
  float* smB = sm + 2176;
  float* smV = sm;
  float* smL = sm + 10368;

  const int t    = threadIdx.x;
  const int blk  = blockIdx.x;
  const int rbase = blk * 8;
  const int b2   = rbase / SPT;
  const int posb = rbase % SPT;
  const int z  = posb / 576;
  const int y  = (posb % 576) / 24;
  const int x0 = posb % 24;

  const int pix_t = t >> 4;
  const int oc_t  = t & 15;
  const int am    = t >> 2;
  const int acin  = (t & 3) * 8;
  const int a_pl  = am >> 3;
  const int a_n   = b2 * 8 + (am & 7);
  const int a_bin = a_n & 1;
  const int a_icin = a_n >> 1;

  float acc[4][16];
  #pragma unroll
  for (int i = 0; i < 4; ++i)
    #pragma unroll
    for (int j = 0; j < 16; ++j) acc[i][j] = 0.f;

  #pragma unroll 1
  for (int tap = 0; tap < 27; ++tap) {
    const int dz = tap / 9, dy = (tap % 9) / 3, dx = tap % 3;
    const int zz = z + dz - 1;
    const int yy = y + dy - 1;
    const int xx = x0 + a_pl + dx - 1;

    float4 va = {0.f, 0.f, 0.f, 0.f}, vb = {0.f, 0.f, 0.f, 0.f};
    if ((unsigned)zz < 24u && (unsigned)yy < 24u && (unsigned)xx < 24u) {
      const float* src = xg + ((((a_bin * 24 + zz) * 24 + yy) * 24 + xx) * 8 + a_icin) * 32 + acin;
      va = *(const float4*)src;
      vb = *(const float4*)(src + 4);
    }
    float4 wv[8];
    const float* wsrc = Wg + tap * 8192 + t * 4;
    #pragma unroll
    for (int k = 0; k < 8; ++k) wv[k] = *(const float4*)(wsrc + k * 1024);

    __syncthreads();
    smA[(acin + 0) * 68 + am] = va.x;
    smA[(acin + 1) * 68 + am] = va.y;
    smA[(acin + 2) * 68 + am] = va.z;
    smA[(acin + 3) * 68 + am] = va.w;
    smA[(acin + 4) * 68 + am] = vb.x;
    smA[(acin + 5) * 68 + am] = vb.y;
    smA[(acin + 6) * 68 + am] = vb.z;
    smA[(acin + 7) * 68 + am] = vb.w;
    #pragma unroll
    for (int k = 0; k < 8; ++k) *(float4*)&smB[k * 1024 + t * 4] = wv[k];
    __syncthreads();

    #pragma unroll 8
    for (int cin = 0; cin < 32; ++cin) {
      const float4 a4  = *(const float4*)&smA[cin * 68 + pix_t * 4];
      const float4 b0  = *(const float4*)&smB[cin * 256 + oc_t * 4];
      const float4 b1  = *(const float4*)&smB[cin * 256 + oc_t * 4 + 64];
      const float4 b2v = *(const float4*)&smB[cin * 256 + oc_t * 4 + 128];
      const float4 b3v = *(const float4*)&smB[cin * 256 + oc_t * 4 + 192];
      const float ar[4] = {a4.x, a4.y, a4.z, a4.w};
      #pragma unroll
      for (int i = 0; i < 4; ++i) {
        acc[i][0]  = fmaf(ar[i], b0.x,  acc[i][0]);
        acc[i][1]  = fmaf(ar[i], b0.y,  acc[i][1]);
        acc[i][2]  = fmaf(ar[i], b0.z,  acc[i][2]);
        acc[i][3]  = fmaf(ar[i], b0.w,  acc[i][3]);
        acc[i][4]  = fmaf(ar[i], b1.x,  acc[i][4]);
        acc[i][5]  = fmaf(ar[i], b1.y,  acc[i][5]);
        acc[i][6]  = fmaf(ar[i], b1.z,  acc[i][6]);
        acc[i][7]  = fmaf(ar[i], b1.w,  acc[i][7]);
        acc[i][8]  = fmaf(ar[i], b2v.x, acc[i][8]);
        acc[i][9]  = fmaf(ar[i], b2v.y, acc[i][9]);
        acc[i][10] = fmaf(ar[i], b2v.z, acc[i][10]);
        acc[i][11] = fmaf(ar[i], b2v.w, acc[i][11]);
        acc[i][12] = fmaf(ar[i], b3v.x, acc[i][12]);
        acc[i][13] = fmaf(ar[i], b3v.y, acc[i][13]);
        acc[i][14] = fmaf(ar[i], b3v.z, acc[i][14]);
        acc[i][15] = fmaf(ar[i], b3v.w, acc[i][15]);
      }
    }
  }
  __syncthreads();

  const int c = t >> 5;
  const int a = t & 31;
  const float bia = bg[t];

  #pragma unroll 1
  for (int pass = 0; pass < 2; ++pass) {
    if ((pix_t >> 3) == pass) {
      const int rl = (pix_t & 7) * 4;
      #pragma unroll
      for (int i = 0; i < 4; ++i) {
        #pragma unroll
        for (int jj = 0; jj < 4; ++jj) {
          float4 v4 = {acc[i][jj * 4 + 0], acc[i][jj * 4 + 1],
                       acc[i][jj * 4 + 2], acc[i][jj * 4 + 3]};
          *(float4*)&smV[(rl + i) * 256 + oc_t * 4 + jj * 64] = v4;
        }
      }
    }
    __syncthreads();

    #pragma unroll 1
    for (int pp = 0; pp < 4; ++pp) {
      const int pl = pass * 4 + pp;
      float v[8];
      #pragma unroll
      for (int ic = 0; ic < 8; ++ic) v[ic] = smV[(pp * 8 + ic) * 256 + t];

      float route[8];
      #pragma unroll 1
      for (int it = 0; it < 3; ++it) {
        if (it == 0) {
          #pragma unroll
          for (int ic = 0; ic < 8; ++ic) route[ic] = 0.125f;
        } else {
          #pragma unroll
          for (int ic = 0; ic < 8; ++ic) {
            float mx = -3.4e38f;
            #pragma unroll
            for (int cc = 0; cc < 8; ++cc) mx = fmaxf(mx, smL[ic * 8 + cc]);
            float s = 0.f;
            #pragma unroll
            for (int cc = 0; cc < 8; ++cc) s += __expf(smL[ic * 8 + cc] - mx);
            route[ic] = __expf(smL[ic * 8 + c] - mx) / s;
          }
        }
        float pre = bia;
        #pragma unroll
        for (int ic = 0; ic < 8; ++ic) pre = fmaf(route[ic], v[ic], pre);

        float ns = redhalf(pre * pre);
        const float nrm = sqrtf(ns);
        const float act = pre * (nrm / (1.0f + ns));

        if (it == 2) {
          outg[(rbase + pl) * 256 + t] = act;
        } else {
          float d[8];
          #pragma unroll
          for (int ic = 0; ic < 8; ++ic) d[ic] = redhalf(v[ic] * act);
          __syncthreads();
          if (a == 0) {
            #pragma unroll
            for (int ic = 0; ic < 8; ++ic)
              smL[ic * 8 + c] = (it == 0) ? d[ic] : smL[ic * 8 + c] + d[ic];
          }
          __syncthreads();
        }
      }
    }
    __syncthreads();
  }
}

extern "C" void kernel_launch(void* const* d_in, const int* in_sizes, int n_in,
                              void* d_out, int out_size, void* d_ws, size_t ws_size,
                              hipStream_t stream) {
  const float* x = (const float*)d_in[0];
  const float* W = (const float*)d_in[1];
  const float* b = (const float*)d_in[2];
  float* out = (float*)d_out;
  (void)in_sizes; (void)n_in; (void)out_size;

  if (ws_size >= 27u * 8192u * sizeof(_Float16)) {
    _Float16* Wh = (_Float16*)d_ws;
    prep_W<<<dim3(27), dim3(256), 0, stream>>>(W, Wh);
    caps_mfma6<<<dim3(3456), dim3(256), 0, stream>>>(x, Wh, b, out);
  } else {
    caps_fused<<<dim3(3456), dim3(256), 0, stream>>>(x, W, b, out);
  }
}

// Round 9
// 354.898 us; speedup vs baseline: 4.5050x; 1.0670x over previous
//
#include <hip/hip_runtime.h>
#include <math.h>

// Conv3DCapsuleLayer: fp16-MFMA implicit-GEMM conv3d + fused 3-iter dynamic routing.
// input_tensor (2,24,24,24,8,32) f32 | W (3,3,3,32,256) f32 | b (1,1,1,8,32) f32
// out = activation (2,24,24,24,8,32) f32
//
// Conv rows n=0..15 map to input (b_in = n&1, ic_in = n>>1)
// Routing votes[b2][ic2] = conv row n = b2*8 + ic2
//
// Round-9 = round-8 (verified, 378us) + two safe changes:
//  (1) __launch_bounds__(256,4): LDS 34.8KB x4 = 139KB < 160KB, VGPR 72 < 128
//      -> 4 blocks/CU resident (was 3). Kernel is latency-bound (MfmaUtil 9%,
//      VALUBusy 30%, occ 32%) so TLP is the global lever.
//  (2) logits table double-buffered per wave (write buf[it&1], read buf[(it-1)&1])
//      -> 3 block barriers per routing pass instead of 6 (write never races reads;
//      end-of-pass barrier redundant since it1-barrier orders all smV reads).

#define SPT 13824   // 24*24*24

typedef __attribute__((ext_vector_type(8))) _Float16 half8;
typedef __attribute__((ext_vector_type(4))) float f32x4;

// reduce over a 32-lane half (masks 16,8,4,2,1) — verified rounds 1-4/8
__device__ __forceinline__ float redhalf(float v) {
  v += __shfl_xor(v, 16);
  v += __shfl_xor(v, 8);
  v += __shfl_xor(v, 4);
  v += __shfl_xor(v, 2);
  v += __shfl_xor(v, 1);
  return v;
}

// W (3,3,3,32,256) fp32 -> Wh[tap][cb(16)][slot(64)][8] fp16, slot = kg*16+nr:
// element (k = kg*8+j, n = cb*16+nr). This is exactly the MFMA B-fragment order.
__global__ void prep_W(const float* __restrict__ W, _Float16* __restrict__ Wh) {
  const int tap = blockIdx.x;
  #pragma unroll
  for (int rep = 0; rep < 4; ++rep) {
    const int idx = rep * 256 + threadIdx.x;   // 0..1023
    const int cb = idx >> 6;
    const int kg = (idx >> 4) & 3;
    const int nr = idx & 15;
    const int n  = cb * 16 + nr;
    half8 o;
    #pragma unroll
    for (int j = 0; j < 8; ++j)
      o[j] = (_Float16)W[(tap * 32 + kg * 8 + j) * 256 + n];
    *(half8*)(Wh + tap * 8192 + idx * 8) = o;
  }
}

__global__ __launch_bounds__(256, 4)
void caps_mfma7(const float* __restrict__ xg, const _Float16* __restrict__ Wh,
                const float* __restrict__ bg, float* __restrict__ outg) {
  // LDS: strip buf0 at 0, buf1 at 17280 (each 17280B); routing aliases:
  // smV f32 [32][264] at 0 (33792B), smLw 4 waves x 2 bufs x 64 f32 at 33792 (2048B)
  __shared__ __align__(16) unsigned char lds[35840];
  float* smV = (float*)lds;

  const int t    = threadIdx.x;
  const int lane = t & 63;
  const int w    = t >> 6;
  // XCD-chunked swizzle: 3456 = 8 XCDs x 432 contiguous blocks
  const int wg   = (blockIdx.x & 7) * 432 + (blockIdx.x >> 3);
  const int rbase = wg * 8;
  const int b2   = rbase / SPT;
  const int posb = rbase % SPT;
  const int z  = posb / 576;
  const int y  = (posb % 576) / 24;
  const int x0 = posb % 24;

  // ---- strip staging mapping (threads 0..239) ----
  const bool stager = t < 240;
  const int sdy  = t / 80;           // 0..2
  const int srem = t % 80;
  const int sxs  = srem >> 3;        // x-slot 0..9
  const int sic  = srem & 7;         // GEMM-row ic
  const int sn   = b2 * 8 + sic;
  const int sbin = sn & 1;
  const int sicin = sn >> 1;
  const int syy  = y + sdy - 1;
  const int sxx  = x0 + sxs - 1;
  const int sR   = (sdy * 10 + sxs) * 8 + sic;      // strip row
  const bool syx_ok = (unsigned)syy < 24u && (unsigned)sxx < 24u;
  const float* sbase = xg + (((sbin * 24) * 24 + (syx_ok ? syy : 0)) * 24 + (syx_ok ? sxx : 0)) * 256 + sicin * 32;

  // ---- A-fragment lane bases (bytes within a strip buffer) ----
  const int lm = lane & 15;
  int abase[4];
  #pragma unroll
  for (int mi = 0; mi < 4; ++mi)
    abase[mi] = ((mi * 2 + (lm >> 3)) * 8 + (lane & 7)) * 72 + (lane >> 4) * 16;

  // B fragment base: Wh + tap*8192 + (w*4+ni)*512 + lane*8  (halves)
  const _Float16* bbase = Wh + w * 2048 + lane * 8;

  f32x4 acc[4][4];
  #pragma unroll
  for (int mi = 0; mi < 4; ++mi)
    #pragma unroll
    for (int ni = 0; ni < 4; ++ni) acc[mi][ni] = (f32x4){0.f, 0.f, 0.f, 0.f};

  // ---- prologue: stage strip for dz=0 (zz = z-1) into buf0 ----
  {
    const int zz = z - 1;
    const bool val = (unsigned)zz < 24u && syx_ok;
    const float* src = sbase + (zz >= 0 ? zz : 0) * 24 * 24 * 256;
    half8 h[4];
    #pragma unroll
    for (int j = 0; j < 4; ++j) {
      float4 qa = val ? *(const float4*)(src + j * 8)     : (float4){0,0,0,0};
      float4 qb = val ? *(const float4*)(src + j * 8 + 4) : (float4){0,0,0,0};
      half8 hh;
      hh[0]=(_Float16)qa.x; hh[1]=(_Float16)qa.y; hh[2]=(_Float16)qa.z; hh[3]=(_Float16)qa.w;
      hh[4]=(_Float16)qb.x; hh[5]=(_Float16)qb.y; hh[6]=(_Float16)qb.z; hh[7]=(_Float16)qb.w;
      h[j] = hh;
    }
    if (stager) {
      unsigned char* dst = lds + sR * 72;
      #pragma unroll
      for (int j = 0; j < 4; ++j) *(half8*)(dst + j * 16) = h[j];
    }
  }
  __syncthreads();

  #pragma unroll 1
  for (int dz = 0; dz < 3; ++dz) {
    // ---- issue + convert next strip (zz = z+dz) early ----
    half8 h[4];
    const bool have = dz < 2;
    {
      const int zz = z + dz;
      const bool val = have && (unsigned)zz < 24u && syx_ok;
      const float* src = sbase + zz * 24 * 24 * 256;
      #pragma unroll
      for (int j = 0; j < 4; ++j) {
        float4 qa = val ? *(const float4*)(src + j * 8)     : (float4){0,0,0,0};
        float4 qb = val ? *(const float4*)(src + j * 8 + 4) : (float4){0,0,0,0};
        half8 hh;
        hh[0]=(_Float16)qa.x; hh[1]=(_Float16)qa.y; hh[2]=(_Float16)qa.z; hh[3]=(_Float16)qa.w;
        hh[4]=(_Float16)qb.x; hh[5]=(_Float16)qb.y; hh[6]=(_Float16)qb.z; hh[7]=(_Float16)qb.w;
        h[j] = hh;
      }
    }

    const unsigned char* sb = lds + (dz & 1) * 17280;
    #pragma unroll 1
    for (int dy = 0; dy < 3; ++dy) {
      const _Float16* bt = bbase + (dz * 9 + dy * 3) * 8192;
      half8 bA0, bA1, bA2, bA3, bB0, bB1, bB2, bB3;
      bA0 = *(const half8*)(bt + 0 * 512);
      bA1 = *(const half8*)(bt + 1 * 512);
      bA2 = *(const half8*)(bt + 2 * 512);
      bA3 = *(const half8*)(bt + 3 * 512);

      // ---- dx = 0 (use A-set, prefetch B-set) ----
      bB0 = *(const half8*)(bt + 8192 + 0 * 512);
      bB1 = *(const half8*)(bt + 8192 + 1 * 512);
      bB2 = *(const half8*)(bt + 8192 + 2 * 512);
      bB3 = *(const half8*)(bt + 8192 + 3 * 512);
      {
        const int imm = dy * 5760;
        half8 af[4];
        #pragma unroll
        for (int mi = 0; mi < 4; ++mi) af[mi] = *(const half8*)(sb + abase[mi] + imm);
        #pragma unroll
        for (int mi = 0; mi < 4; ++mi) {
          acc[mi][0] = __builtin_amdgcn_mfma_f32_16x16x32_f16(af[mi], bA0, acc[mi][0], 0, 0, 0);
          acc[mi][1] = __builtin_amdgcn_mfma_f32_16x16x32_f16(af[mi], bA1, acc[mi][1], 0, 0, 0);
          acc[mi][2] = __builtin_amdgcn_mfma_f32_16x16x32_f16(af[mi], bA2, acc[mi][2], 0, 0, 0);
          acc[mi][3] = __builtin_amdgcn_mfma_f32_16x16x32_f16(af[mi], bA3, acc[mi][3], 0, 0, 0);
        }
      }
      // ---- dx = 1 (use B-set, prefetch A-set for dx=2) ----
      bA0 = *(const half8*)(bt + 16384 + 0 * 512);
      bA1 = *(const half8*)(bt + 16384 + 1 * 512);
      bA2 = *(const half8*)(bt + 16384 + 2 * 512);
      bA3 = *(const half8*)(bt + 16384 + 3 * 512);
      {
        const int imm = dy * 5760 + 576;
        half8 af[4];
        #pragma unroll
        for (int mi = 0; mi < 4; ++mi) af[mi] = *(const half8*)(sb + abase[mi] + imm);
        #pragma unroll
        for (int mi = 0; mi < 4; ++mi) {
          acc[mi][0] = __builtin_amdgcn_mfma_f32_16x16x32_f16(af[mi], bB0, acc[mi][0], 0, 0, 0);
          acc[mi][1] = __builtin_amdgcn_mfma_f32_16x16x32_f16(af[mi], bB1, acc[mi][1], 0, 0, 0);
          acc[mi][2] = __builtin_amdgcn_mfma_f32_16x16x32_f16(af[mi], bB2, acc[mi][2], 0, 0, 0);
          acc[mi][3] = __builtin_amdgcn_mfma_f32_16x16x32_f16(af[mi], bB3, acc[mi][3], 0, 0, 0);
        }
      }
      // ---- dx = 2 (use A-set) ----
      {
        const int imm = dy * 5760 + 1152;
        half8 af[4];
        #pragma unroll
        for (int mi = 0; mi < 4; ++mi) af[mi] = *(const half8*)(sb + abase[mi] + imm);
        #pragma unroll
        for (int mi = 0; mi < 4; ++mi) {
          acc[mi][0] = __builtin_amdgcn_mfma_f32_16x16x32_f16(af[mi], bA0, acc[mi][0], 0, 0, 0);
          acc[mi][1] = __builtin_amdgcn_mfma_f32_16x16x32_f16(af[mi], bA1, acc[mi][1], 0, 0, 0);
          acc[mi][2] = __builtin_amdgcn_mfma_f32_16x16x32_f16(af[mi], bA2, acc[mi][2], 0, 0, 0);
          acc[mi][3] = __builtin_amdgcn_mfma_f32_16x16x32_f16(af[mi], bA3, acc[mi][3], 0, 0, 0);
        }
      }
    }

    if (have && stager) {
      unsigned char* dst = lds + ((dz + 1) & 1) * 17280 + sR * 72;
      #pragma unroll
      for (int j = 0; j < 4; ++j) *(half8*)(dst + j * 16) = h[j];
    }
    __syncthreads();
  }

  // ---------------- routing (wave-parallel, verified primitives only) ----------------
  // lane = (ch = l>>5, al = l&31). Wave w routes position pl = pass*4 + w.
  // Lane owns atom al of capsules c = 2q+ch (q=0..3).
  // Logits: per-wave 8x8 table in LDS, DOUBLE-BUFFERED (write buf[it&1], read
  // buf[(it-1)&1]) -> one barrier per iteration, no read/write hazard.
  const int ch = lane >> 5;
  const int al = lane & 31;
  float* smLw = (float*)(lds + 33792) + w * 128;   // [buf][ic*8+c], buf stride 64

  float bia[4];
  #pragma unroll
  for (int q = 0; q < 4; ++q) bia[q] = bg[(2 * q + ch) * 32 + al];

  #pragma unroll 1
  for (int pass = 0; pass < 2; ++pass) {
    // dump rows [pass*32, pass*32+32) of votes — verbatim round-4 dump
    #pragma unroll
    for (int mh = 0; mh < 2; ++mh) {
      const int mi = pass * 2 + mh;
      #pragma unroll
      for (int ni = 0; ni < 4; ++ni) {
        #pragma unroll
        for (int j = 0; j < 4; ++j) {
          const int rl  = mh * 16 + (lane >> 4) * 4 + j;        // 0..31
          const int col = w * 64 + ni * 16 + (lane & 15);
          smV[rl * 264 + col] = acc[mi][ni][j];
        }
      }
    }
    __syncthreads();

    // this wave's position: v[ic][q] = votes[ic][capsule 2q+ch][atom al]
    float v[8][4];
    #pragma unroll
    for (int ic = 0; ic < 8; ++ic)
      #pragma unroll
      for (int q = 0; q < 4; ++q)
        v[ic][q] = smV[(w * 8 + ic) * 264 + (2 * q + ch) * 32 + al];

    #pragma unroll 1
    for (int it = 0; it < 3; ++it) {
      // preactivate (softmax from per-wave LDS table)
      const float* Lrd = smLw + ((it + 1) & 1) * 64;   // it=1 -> buf0, it=2 -> buf1
      float pre[4];
      #pragma unroll
      for (int q = 0; q < 4; ++q) pre[q] = bia[q];
      if (it == 0) {
        #pragma unroll
        for (int ic = 0; ic < 8; ++ic)
          #pragma unroll
          for (int q = 0; q < 4; ++q)
            pre[q] = fmaf(0.125f, v[ic][q], pre[q]);
      } else {
        #pragma unroll
        for (int ic = 0; ic < 8; ++ic) {
          float Lv[8];
          #pragma unroll
          for (int cc = 0; cc < 8; ++cc) Lv[cc] = Lrd[ic * 8 + cc];
          float mx = Lv[0];
          #pragma unroll
          for (int cc = 1; cc < 8; ++cc) mx = fmaxf(mx, Lv[cc]);
          float e[8];
          float s = 0.f;
          #pragma unroll
          for (int cc = 0; cc < 8; ++cc) { e[cc] = __expf(Lv[cc] - mx); s += e[cc]; }
          const float inv = 1.0f / s;
          #pragma unroll
          for (int q = 0; q < 4; ++q)
            pre[q] = fmaf(e[2 * q + ch] * inv, v[ic][q], pre[q]);
        }
      }

      // squash: norm over atoms (32-lane half reduce, verified primitive)
      float act[4];
      #pragma unroll
      for (int q = 0; q < 4; ++q) {
        float ns = redhalf(pre[q] * pre[q]);
        act[q] = pre[q] * (sqrtf(ns) / (1.0f + ns));
      }

      if (it == 2) {
        const int pl = pass * 4 + w;
        #pragma unroll
        for (int q = 0; q < 4; ++q)
          outg[(rbase + pl) * 256 + (2 * q + ch) * 32 + al] = act[q];
      } else {
        // distances (half-reduce over atoms) -> logits into write-buffer
        float d[8][4];
        #pragma unroll
        for (int ic = 0; ic < 8; ++ic)
          #pragma unroll
          for (int q = 0; q < 4; ++q)
            d[ic][q] = redhalf(v[ic][q] * act[q]);
        float* Lwr = smLw + (it & 1) * 64;           // it=0 -> buf0, it=1 -> buf1
        if (al == 0) {
          #pragma unroll
          for (int ic = 0; ic < 8; ++ic)
            #pragma unroll
            for (int q = 0; q < 4; ++q) {
              const int cc = 2 * q + ch;
              Lwr[ic * 8 + cc] = (it == 0) ? d[ic][q] : Lrd[ic * 8 + cc] + d[ic][q];
            }
        }
        __syncthreads();   // write-buffer visible; readers of old buffer unharmed
      }
    }
    // no end-of-pass barrier needed: the it1 barrier already ordered all
    // of this pass's smV reads before any wave reaches the next dump.
  }
}

// ---------------- fallback: fp32 kernel (used only if ws too small) ----------------
__global__ __launch_bounds__(256, 3)
void caps_fused(const float* __restrict__ xg, const float* __restrict__ Wg,
                const float* __restrict__ bg, float* __restrict__ outg) {
  __shared__ __align__(16) float sm[10432];
  float* smA = sm;
  float* smB = sm + 2176;
  float* smV = sm;
  float* smL = sm + 10368;

  const int t    = threadIdx.x;
  const int blk  = blockIdx.x;
  const int rbase = blk * 8;
  const int b2   = rbase / SPT;
  const int posb = rbase % SPT;
  const int z  = posb / 576;
  const int y  = (posb % 576) / 24;
  const int x0 = posb % 24;

  const int pix_t = t >> 4;
  const int oc_t  = t & 15;
  const int am    = t >> 2;
  const int acin  = (t & 3) * 8;
  const int a_pl  = am >> 3;
  const int a_n   = b2 * 8 + (am & 7);
  const int a_bin = a_n & 1;
  const int a_icin = a_n >> 1;

  float acc[4][16];
  #pragma unroll
  for (int i = 0; i < 4; ++i)
    #pragma unroll
    for (int j = 0; j < 16; ++j) acc[i][j] = 0.f;

  #pragma unroll 1
  for (int tap = 0; tap < 27; ++tap) {
    const int dz = tap / 9, dy = (tap % 9) / 3, dx = tap % 3;
    const int zz = z + dz - 1;
    const int yy = y + dy - 1;
    const int xx = x0 + a_pl + dx - 1;

    float4 va = {0.f, 0.f, 0.f, 0.f}, vb = {0.f, 0.f, 0.f, 0.f};
    if ((unsigned)zz < 24u && (unsigned)yy < 24u && (unsigned)xx < 24u) {
      const float* src = xg + ((((a_bin * 24 + zz) * 24 + yy) * 24 + xx) * 8 + a_icin) * 32 + acin;
      va = *(const float4*)src;
      vb = *(const float4*)(src + 4);
    }
    float4 wv[8];
    const float* wsrc = Wg + tap * 8192 + t * 4;
    #pragma unroll
    for (int k = 0; k < 8; ++k) wv[k] = *(const float4*)(wsrc + k * 1024);

    __syncthreads();
    smA[(acin + 0) * 68 + am] = va.x;
    smA[(acin + 1) * 68 + am] = va.y;
    smA[(acin + 2) * 68 + am] = va.z;
    smA[(acin + 3) * 68 + am] = va.w;
    smA[(acin + 4) * 68 + am] = vb.x;
    smA[(acin + 5) * 68 + am] = vb.y;
    smA[(acin + 6) * 68 + am] = vb.z;
    smA[(acin + 7) * 68 + am] = vb.w;
    #pragma unroll
    for (int k = 0; k < 8; ++k) *(float4*)&smB[k * 1024 + t * 4] = wv[k];
    __syncthreads();

    #pragma unroll 8
    for (int cin = 0; cin < 32; ++cin) {
      const float4 a4  = *(const float4*)&smA[cin * 68 + pix_t * 4];
      const float4 b0  = *(const float4*)&smB[cin * 256 + oc_t * 4];
      const float4 b1  = *(const float4*)&smB[cin * 256 + oc_t * 4 + 64];
      const float4 b2v = *(const float4*)&smB[cin * 256 + oc_t * 4 + 128];
      const float4 b3v = *(const float4*)&smB[cin * 256 + oc_t * 4 + 192];
      const float ar[4] = {a4.x, a4.y, a4.z, a4.w};
      #pragma unroll
      for (int i = 0; i < 4; ++i) {
        acc[i][0]  = fmaf(ar[i], b0.x,  acc[i][0]);
        acc[i][1]  = fmaf(ar[i], b0.y,  acc[i][1]);
        acc[i][2]  = fmaf(ar[i], b0.z,  acc[i][2]);
        acc[i][3]  = fmaf(ar[i], b0.w,  acc[i][3]);
        acc[i][4]  = fmaf(ar[i], b1.x,  acc[i][4]);
        acc[i][5]  = fmaf(ar[i], b1.y,  acc[i][5]);
        acc[i][6]  = fmaf(ar[i], b1.z,  acc[i][6]);
        acc[i][7]  = fmaf(ar[i], b1.w,  acc[i][7]);
        acc[i][8]  = fmaf(ar[i], b2v.x, acc[i][8]);
        acc[i][9]  = fmaf(ar[i], b2v.y, acc[i][9]);
        acc[i][10] = fmaf(ar[i], b2v.z, acc[i][10]);
        acc[i][11] = fmaf(ar[i], b2v.w, acc[i][11]);
        acc[i][12] = fmaf(ar[i], b3v.x, acc[i][12]);
        acc[i][13] = fmaf(ar[i], b3v.y, acc[i][13]);
        acc[i][14] = fmaf(ar[i], b3v.z, acc[i][14]);
        acc[i][15] = fmaf(ar[i], b3v.w, acc[i][15]);
      }
    }
  }
  __syncthreads();

  const int c = t >> 5;
  const int a = t & 31;
  const float bia = bg[t];

  #pragma unroll 1
  for (int pass = 0; pass < 2; ++pass) {
    if ((pix_t >> 3) == pass) {
      const int rl = (pix_t & 7) * 4;
      #pragma unroll
      for (int i = 0; i < 4; ++i) {
        #pragma unroll
        for (int jj = 0; jj < 4; ++jj) {
          float4 v4 = {acc[i][jj * 4 + 0], acc[i][jj * 4 + 1],
                       acc[i][jj * 4 + 2], acc[i][jj * 4 + 3]};
          *(float4*)&smV[(rl + i) * 256 + oc_t * 4 + jj * 64] = v4;
        }
      }
    }
    __syncthreads();

    #pragma unroll 1
    for (int pp = 0; pp < 4; ++pp) {
      const int pl = pass * 4 + pp;
      float v[8];
      #pragma unroll
      for (int ic = 0; ic < 8; ++ic) v[ic] = smV[(pp * 8 + ic) * 256 + t];

      float route[8];
      #pragma unroll 1
      for (int it = 0; it < 3; ++it) {
        if (it == 0) {
          #pragma unroll
          for (int ic = 0; ic < 8; ++ic) route[ic] = 0.125f;
        } else {
          #pragma unroll
          for (int ic = 0; ic < 8; ++ic) {
            float mx = -3.4e38f;
            #pragma unroll
            for (int cc = 0; cc < 8; ++cc) mx = fmaxf(mx, smL[ic * 8 + cc]);
            float s = 0.f;
            #pragma unroll
            for (int cc = 0; cc < 8; ++cc) s += __expf(smL[ic * 8 + cc] - mx);
            route[ic] = __expf(smL[ic * 8 + c] - mx) / s;
          }
        }
        float pre = bia;
        #pragma unroll
        for (int ic = 0; ic < 8; ++ic) pre = fmaf(route[ic], v[ic], pre);

        float ns = redhalf(pre * pre);
        const float nrm = sqrtf(ns);
        const float act = pre * (nrm / (1.0f + ns));

        if (it == 2) {
          outg[(rbase + pl) * 256 + t] = act;
        } else {
          float d[8];
          #pragma unroll
          for (int ic = 0; ic < 8; ++ic) d[ic] = redhalf(v[ic] * act);
          __syncthreads();
          if (a == 0) {
            #pragma unroll
            for (int ic = 0; ic < 8; ++ic)
              smL[ic * 8 + c] = (it == 0) ? d[ic] : smL[ic * 8 + c] + d[ic];
          }
          __syncthreads();
        }
      }
    }
    __syncthreads();
  }
}

extern "C" void kernel_launch(void* const* d_in, const int* in_sizes, int n_in,
                              void* d_out, int out_size, void* d_ws, size_t ws_size,
                              hipStream_t stream) {
  const float* x = (const float*)d_in[0];
  const float* W = (const float*)d_in[1];
  const float* b = (const float*)d_in[2];
  float* out = (float*)d_out;
  (void)in_sizes; (void)n_in; (void)out_size;

  if (ws_size >= 27u * 8192u * sizeof(_Float16)) {
    _Float16* Wh = (_Float16*)d_ws;
    prep_W<<<dim3(27), dim3(256), 0, stream>>>(W, Wh);
    caps_mfma7<<<dim3(3456), dim3(256), 0, stream>>>(x, Wh, b, out);
  } else {
    caps_fused<<<dim3(3456), dim3(256), 0, stream>>>(x, W, b, out);
  }
}